// Round 6
// baseline (640.863 us; speedup 1.0000x reference)
//
#include <hip/hip_runtime.h>

// MonarchAttentionPerformer MI355X — round 10: KQ intermediate eliminated.
//   wtx_k = K·w^T,  K = x·Wk^T + bk   ==>   wtx_k = x·(w·Wk)^T + (w·bk)
// so G2k/G2q read x16 directly with precombined weights Wkw/Wqw (f16) and
// biases bkw/bqw (f32); G1 computes K,Q only for the xd row-norms (no store),
// writing just V^T. Saves 100 MB KQ write + 100 MB cold KQ read.
// Round-9's G5-elimination (Z = Wp·kptv) retained.
//
//   G1: x16 @ WkqvT -> xd atomics (K,Q norms; not stored), V^T bf16 [n][t]
//   Gw: Wkw[part] = w16 @ WkqvN[part]^T (f16 store)   [384 x 768 x 768] x2
//   G2k: x16 @ Wkw -> kpT bf16 [m][t] + ksum atomics  (bias bkw in exp)
//   G2q: x16 @ Wqw -> qp bf16 [t][m] + D atomics      (bias bqw in exp)
//   G3: V^T @ kpT^T (split-K=4) -> kptv32 partials f32 [s][n][m]
//   reduce_kptv_t: sum 4 partials -> kptvT bf16 [b][m][n]
//   Gz: WprojT @ kptvT^T -> Z bf16 [b][j][m]
//   G45: (qp @ Z^T)/(D+eps) + bias -> out fp32

#define NTOK   32768
#define RSQRTM 0.05103103630798288f   // 1/sqrt(384)

typedef _Float16 f16;
typedef f16   f16x8 __attribute__((ext_vector_type(8)));
typedef f16   f16x4 __attribute__((ext_vector_type(4)));
typedef short s16x8 __attribute__((ext_vector_type(8)));
typedef float f32x4 __attribute__((ext_vector_type(4)));

typedef const void __attribute__((address_space(1))) gv_t;
typedef void       __attribute__((address_space(3))) lv_t;
#define GLL16(g, l) __builtin_amdgcn_global_load_lds((gv_t*)(g), (lv_t*)(l), 16, 0, 0)

__device__ __forceinline__ float b2f(unsigned short u){
  union{unsigned int i; float f;} v; v.i = ((unsigned int)u)<<16; return v.f;
}
__device__ __forceinline__ unsigned short f2b(float f){
  union{float f; unsigned int i;} v; v.f = f;
  unsigned int x = v.i;
  x += 0x7fffu + ((x>>16)&1u);
  return (unsigned short)(x>>16);
}

template<typename T> struct MfmaOp;
template<> struct MfmaOp<f16> {
  typedef f16x8 frag;
  static __device__ __forceinline__ f32x4 run(frag a, frag b, f32x4 c){
    return __builtin_amdgcn_mfma_f32_16x16x32_f16(a, b, c, 0, 0, 0);
  }
};
template<> struct MfmaOp<short> {   // bf16 payload
  typedef s16x8 frag;
  static __device__ __forceinline__ f32x4 run(frag a, frag b, f32x4 c){
    return __builtin_amdgcn_mfma_f32_16x16x32_bf16(a, b, c, 0, 0, 0);
  }
};

// ---------------- converters / builders ----------------
__global__ void cvt16(const float4* __restrict__ src, f16* __restrict__ dst, int n4){
  const int i = blockIdx.x*256 + threadIdx.x;
  if (i >= n4) return;
  const float4 v = src[i];
  f16x4 h; h[0]=(f16)v.x; h[1]=(f16)v.y; h[2]=(f16)v.z; h[3]=(f16)v.w;
  *reinterpret_cast<f16x4*>(dst + 4*(long)i) = h;
}
// WkqvT[j][i] (output-major) and, for the K/Q parts, WkqvN[i][j] (input-major,
// feeds the Gw combine as the Bt operand).
__global__ void build_wkqvT(const float* __restrict__ w1, const float* __restrict__ w2,
                            f16* __restrict__ Wt, f16* __restrict__ Wn){
  const int idx = blockIdx.x*256 + threadIdx.x;   // 2304*768
  const int j = idx / 768, i = idx % 768;
  const int k = i / 192, p = i % 192;
  const int s = j >> 2,  l = j & 3;
  float acc = 0.f;
  #pragma unroll 4
  for(int u=0; u<48; ++u)
    acc += w1[(k*192 + l*48+u)*192 + p] * w2[(l*576+s)*192 + 4*u+k];
  Wt[idx] = (f16)acc;
  if (j < 1536) Wn[(long)i*1536 + j] = (f16)acc;
}
__global__ void build_wprojT(const float* __restrict__ w1, const float* __restrict__ w2,
                             unsigned short* __restrict__ Wt){
  const int idx = blockIdx.x*256 + threadIdx.x;   // 768*768
  const int j = idx / 768, i = idx % 768;
  const int k = i / 192, p = i % 192;
  const int s = j >> 2,  l = j & 3;
  float acc = 0.f;
  #pragma unroll 4
  for(int u=0; u<48; ++u)
    acc += w1[(k*192 + l*48+u)*192 + p] * w2[(l*192+s)*192 + 4*u+k];
  Wt[idx] = f2b(acc);
}
// bkw[part*384+m] = sum_j kqv_b[part*768+j] * w[m][j]   (part 0=K, 1=Q)
__global__ void build_bkw(const float* __restrict__ b, const f16* __restrict__ w16,
                          float* __restrict__ bkw){
  const int idx = blockIdx.x*256 + threadIdx.x;   // 768
  if (idx >= 768) return;
  const int part = idx / 384, m = idx % 384;
  const float* bp = b + part*768;
  const f16*  wp = w16 + (long)m*768;
  float acc = 0.f;
  for(int j=0; j<768; ++j) acc += bp[j]*(float)wp[j];
  bkw[idx] = acc;
}
// kptvT[b][m][n] = bf16( sum_s kptv32[(b*4+s)][n][m] )  — 64x64 LDS transpose
__global__ void reduce_kptv_t(const float* __restrict__ p32, unsigned short* __restrict__ o){
  __shared__ float t[64][65];
  const int b = blockIdx.z, n0 = blockIdx.x*64, m0 = blockIdx.y*64;
  const int tx = threadIdx.x & 63, ty = threadIdx.x >> 6;
  const float* base = p32 + (long)b*4*294912;
  #pragma unroll 4
  for (int r = 0; r < 16; ++r){
    const int n = n0 + ty*16 + r;
    const int idx = n*384 + m0 + tx;
    t[tx][ty*16+r] = base[idx] + base[294912+idx] + base[2*294912+idx] + base[3*294912+idx];
  }
  __syncthreads();
  unsigned short* ob = o + (long)b*294912;
  #pragma unroll 4
  for (int r = 0; r < 16; ++r){
    const int m = m0 + ty*16 + r;
    ob[(long)m*768 + n0 + tx] = f2b(t[ty*16+r][tx]);
  }
}

// ---------------- MFMA GEMM, BK=64, XOR-swizzled LDS ----------------
// C[M][N] = A[M][K] * Bt[N][K]^T. 256 thr = 4 waves (2x2), 16x16x32 MFMA.
// LDS: row-major chunks of 8 elems; chunk j of row m stored at slot j^(m&7).
// EPI: 0 G1  (xd norm atomics for K/Q, V^T bf16 store; NO KQ store)
//      1 G2k (exp(c+bias-xd) -> kpT transposed; ksum partials -> aux2 atomics)
//      2 G2q (exp(c+bias-xd) -> qp; D partials -> out2 atomics, ksum from aux2)
//      3 G3  (fp32 partial store, split-K)
//      6 Gz  (bf16 store, batched)
//      7 G45 (acc/(D[t]+eps) + bias -> fp32, batched)
//      8 Gw  (f16 store, batched)
template<typename T, int BM, int BN, int EPI, int SPLIT>
__global__ __launch_bounds__(256)
void mgemm(const T* __restrict__ A, int lda, long aB,
           const T* __restrict__ Bt, int ldb, long bB,
           int K, void* __restrict__ out, int ldo, long outB,
           void* __restrict__ out2,
           const float* __restrict__ aux, long auxB,
           float* __restrict__ aux2,
           const float* __restrict__ bias){
  constexpr int MT = BM/32, NT = BN/32;
  constexpr int IA = BM/32, IB = BN/32;   // GLL16 insts per wave per iter
  __shared__ T As[BM*64];
  __shared__ T Bs[BN*64];
  typedef typename MfmaOp<T>::frag frag_t;

  const int tid = threadIdx.x, lane = tid & 63, w = tid >> 6;
  const int wm = w >> 1, wn = w & 1;
  const int ln = lane & 15, q = lane >> 4;
  const int bz = blockIdx.z;
  const int batch = bz / SPLIT;
  const int kstart = (bz % SPLIT) * K;
  const long m0 = (long)blockIdx.y * BM;
  const int  n0 = blockIdx.x * BN;
  const T* Ab = A  + (long)batch*aB;
  const T* Bb = Bt + (long)batch*bB;

  f32x4 acc[MT][NT];
  const f32x4 zero = {0.f, 0.f, 0.f, 0.f};
  #pragma unroll
  for(int i=0;i<MT;i++)
    #pragma unroll
    for(int j=0;j<NT;j++) acc[i][j] = zero;

  for (int k0 = kstart; k0 < kstart + K; k0 += 64){
    __syncthreads();
    #pragma unroll
    for (int i = 0; i < IA; ++i){
      const int e = (w*IA + i)*64 + lane;
      const int m = e >> 3, j = (e & 7) ^ (m & 7);
      GLL16(Ab + (m0 + m)*lda + k0 + j*8, As + (size_t)(w*IA + i)*512);
    }
    #pragma unroll
    for (int i = 0; i < IB; ++i){
      const int e = (w*IB + i)*64 + lane;
      const int n = e >> 3, j = (e & 7) ^ (n & 7);
      GLL16(Bb + (long)(n0 + n)*ldb + k0 + j*8, Bs + (size_t)(w*IB + i)*512);
    }
    __syncthreads();

    #pragma unroll
    for (int kk = 0; kk < 2; ++kk){
      frag_t a[MT], b[NT];
      #pragma unroll
      for (int mt=0; mt<MT; ++mt){
        const int r = wm*MT*16 + mt*16 + ln;
        a[mt] = *reinterpret_cast<const frag_t*>(&As[(r*8 + ((kk*4+q) ^ (r&7)))*8]);
      }
      #pragma unroll
      for (int nt=0; nt<NT; ++nt){
        const int r = wn*NT*16 + nt*16 + ln;
        b[nt] = *reinterpret_cast<const frag_t*>(&Bs[(r*8 + ((kk*4+q) ^ (r&7)))*8]);
      }
      #pragma unroll
      for (int mt=0; mt<MT; ++mt)
        #pragma unroll
        for (int nt=0; nt<NT; ++nt)
          acc[mt][nt] = MfmaOp<T>::run(a[mt], b[nt], acc[mt][nt]);
    }
  }

  // ---- epilogues ----
  if constexpr(EPI==1){               // G2k: kpT + ksum fusion (bias in exp)
    const int b = (int)(m0 >> 12);
    float cs[NT];
    #pragma unroll
    for(int nt=0;nt<NT;nt++) cs[nt]=0.f;
    #pragma unroll
    for (int mt=0; mt<MT; ++mt){
      const long mbase = m0 + wm*MT*16 + mt*16 + q*4;
      float xv[4];
      #pragma unroll
      for(int r=0;r<4;r++) xv[r] = aux[mbase + r];
      #pragma unroll
      for (int nt=0; nt<NT; ++nt){
        const int n = n0 + wn*NT*16 + nt*16 + ln;
        const f32x4 c = acc[mt][nt];
        const float bn = bias[n];
        ushort4 v;
        v.x = f2b(__expf(c[0]+bn-xv[0])*RSQRTM);
        v.y = f2b(__expf(c[1]+bn-xv[1])*RSQRTM);
        v.z = f2b(__expf(c[2]+bn-xv[2])*RSQRTM);
        v.w = f2b(__expf(c[3]+bn-xv[3])*RSQRTM);
        *reinterpret_cast<ushort4*>(&((unsigned short*)out)[(long)n*ldo + mbase]) = v;
        cs[nt] += b2f(v.x)+b2f(v.y)+b2f(v.z)+b2f(v.w);
      }
    }
    #pragma unroll
    for (int nt=0; nt<NT; ++nt){
      cs[nt] += __shfl_xor(cs[nt], 16);
      cs[nt] += __shfl_xor(cs[nt], 32);
      if (lane < 16)
        atomicAdd(&aux2[b*384 + n0 + wn*NT*16 + nt*16 + lane], cs[nt]);
    }
    return;
  }

  #pragma unroll
  for (int mt=0; mt<MT; ++mt){
    const long mbase = m0 + wm*MT*16 + mt*16 + q*4;
    if constexpr(EPI==0){             // G1: xd norms (K,Q) + V^T store
      const int nw = n0 + wn*NT*16;
      const int part = nw / 768;      // 0=K, 1=Q, 2=V (wave-uniform)
      float p[4] = {0.f,0.f,0.f,0.f};
      #pragma unroll
      for (int nt=0; nt<NT; ++nt){
        const int n = nw + nt*16 + ln;
        const f32x4 c = acc[mt][nt];
        const float bv = aux[n];
        if (part < 2){
          #pragma unroll
          for(int r=0;r<4;r++){
            const f16 h = (f16)(c[r] + bv);   // same rounding as old stored KQ
            const float hf = (float)h;
            p[r] += hf*hf;
          }
        } else {
          unsigned short* VT = (unsigned short*)out2;
          ushort4 v;
          v.x = f2b(c[0]+bv); v.y = f2b(c[1]+bv); v.z = f2b(c[2]+bv); v.w = f2b(c[3]+bv);
          *reinterpret_cast<ushort4*>(&VT[(long)(n-1536)*32768 + mbase]) = v;
        }
      }
      if (part < 2){
        #pragma unroll
        for(int r=0;r<4;r++){
          #pragma unroll
          for(int mask=1; mask<16; mask<<=1) p[r] += __shfl_xor(p[r], mask);
        }
        if (ln == 0){
          #pragma unroll
          for(int r=0;r<4;r++)
            atomicAdd(&aux2[part*NTOK + mbase + r], 0.5f*p[r]);
        }
      }
    } else if constexpr(EPI==2){      // G2q: qp + D fusion (bias in exp)
      const int b = (int)(m0 >> 12);
      float xv[4], dp[4] = {0.f,0.f,0.f,0.f};
      #pragma unroll
      for(int r=0;r<4;r++) xv[r] = aux[mbase + r];
      #pragma unroll
      for (int nt=0; nt<NT; ++nt){
        const int n = n0 + wn*NT*16 + nt*16 + ln;
        const f32x4 c = acc[mt][nt];
        const float bn = bias[n];
        const float ksn = aux2[b*384 + n];
        #pragma unroll
        for(int r=0;r<4;r++){
          const unsigned short h = f2b(__expf(c[r]+bn-xv[r])*RSQRTM);
          ((unsigned short*)out)[(mbase+r)*ldo + n] = h;
          dp[r] += b2f(h)*ksn;
        }
      }
      #pragma unroll
      for(int r=0;r<4;r++){
        #pragma unroll
        for(int mask=1; mask<16; mask<<=1) dp[r] += __shfl_xor(dp[r], mask);
      }
      if (ln == 0){
        #pragma unroll
        for(int r=0;r<4;r++)
          atomicAdd(&((float*)out2)[mbase + r], dp[r]);
      }
    } else if constexpr(EPI==3){      // G3: fp32 partial
      float* o = (float*)out + (long)bz*outB;
      #pragma unroll
      for (int nt=0; nt<NT; ++nt){
        const int n = n0 + wn*NT*16 + nt*16 + ln;
        const f32x4 c = acc[mt][nt];
        #pragma unroll
        for(int r=0;r<4;r++) o[(mbase+r)*ldo + n] = c[r];
      }
    } else if constexpr(EPI==6){      // Gz: bf16 store, batched
      unsigned short* o = (unsigned short*)out + (long)bz*outB;
      #pragma unroll
      for (int nt=0; nt<NT; ++nt){
        const int n = n0 + wn*NT*16 + nt*16 + ln;
        const f32x4 c = acc[mt][nt];
        #pragma unroll
        for(int r=0;r<4;r++) o[(mbase+r)*ldo + n] = f2b(c[r]);
      }
    } else if constexpr(EPI==7){      // G45: /(D+eps) + bias -> fp32, batched
      float* o = (float*)out + (long)bz*outB;
      float xv[4];
      #pragma unroll
      for(int r=0;r<4;r++) xv[r] = 1.f/(aux[bz*auxB + mbase + r] + 1e-8f);
      #pragma unroll
      for (int nt=0; nt<NT; ++nt){
        const int n = n0 + wn*NT*16 + nt*16 + ln;
        const f32x4 c = acc[mt][nt];
        const float bv = aux2[n];
        #pragma unroll
        for(int r=0;r<4;r++) o[(mbase+r)*ldo + n] = c[r]*xv[r] + bv;
      }
    } else if constexpr(EPI==8){      // Gw: f16 store, batched
      f16* o = (f16*)out + (long)bz*outB;
      #pragma unroll
      for (int nt=0; nt<NT; ++nt){
        const int n = n0 + wn*NT*16 + nt*16 + ln;
        const f32x4 c = acc[mt][nt];
        #pragma unroll
        for(int r=0;r<4;r++) o[(mbase+r)*ldo + n] = (f16)c[r];
      }
    }
  }
}

// ---------------- launcher ----------------
extern "C" void kernel_launch(void* const* d_in, const int* in_sizes, int n_in,
                              void* d_out, int out_size, void* d_ws, size_t ws_size,
                              hipStream_t stream){
  (void)in_sizes; (void)n_in; (void)out_size;
  const float* x       = (const float*)d_in[0];
  const float* kqv_w1  = (const float*)d_in[1];
  const float* kqv_w2  = (const float*)d_in[2];
  const float* kqv_b   = (const float*)d_in[3];
  const float* proj_w1 = (const float*)d_in[4];
  const float* proj_w2 = (const float*)d_in[5];
  const float* proj_b  = (const float*)d_in[6];
  const float* w       = (const float*)d_in[7];
  char* ws = (char*)d_ws;

  const size_t o_WkqvT  = 0;          // 2304*768 f16   =   3,538,944
  const size_t o_WkqvN  = 3538944;    // 768*1536 f16   =   2,359,296
  const size_t o_WprojT = 5898240;    // 768*768 bf16   =   1,179,648
  const size_t o_w16    = 7077888;    // 384*768 f16    =     589,824
  const size_t o_Wkw    = 7667712;    // 2*384*768 f16  =   1,179,648
  const size_t o_bkw    = 8847360;    // 768 f32        =       3,072
  const size_t o_x16    = 8850432;    // 32768*768 f16  =  50,331,648
  const size_t o_VT     = 59182080;   // 768*32768 bf16 =  50,331,648
  const size_t o_xd     = 109513728;  // 2*32768 f32    =     262,144 ┐
  const size_t o_ksum   = 109775872;  // 3072 f32       =      12,288 │ zero block
  const size_t o_Dv     = 109788160;  // 32768 f32      =     131,072 ┘
  const size_t o_kpT    = 109919232;  // 384*32768 bf16 =  25,165,824
  const size_t o_qp     = 135085056;  // 32768*384 bf16 =  25,165,824
  const size_t o_kptv32 = 160250880;  // 32*294912 f32  =  37,748,736
  const size_t o_kptvT  = 197999616;  // 8*294912 bf16  =   4,718,592
  const size_t o_Z      = 202718208;  // 8*294912 bf16  =   4,718,592
  const size_t TOTAL    = 207436800;
  if (ws_size < TOTAL) return;

  f16*            WkqvT  = (f16*)(ws + o_WkqvT);
  f16*            WkqvN  = (f16*)(ws + o_WkqvN);
  short*          WprojT = (short*)(ws + o_WprojT);
  f16*            w16    = (f16*)(ws + o_w16);
  f16*            Wkw    = (f16*)(ws + o_Wkw);
  float*          bkw    = (float*)(ws + o_bkw);
  f16*            x16    = (f16*)(ws + o_x16);
  short*          VT     = (short*)(ws + o_VT);
  float*          xd     = (float*)(ws + o_xd);
  float*          ksum   = (float*)(ws + o_ksum);
  float*          Dv     = (float*)(ws + o_Dv);
  short*          kpT    = (short*)(ws + o_kpT);
  short*          qp     = (short*)(ws + o_qp);
  float*          kptv32 = (float*)(ws + o_kptv32);
  unsigned short* kptvT  = (unsigned short*)(ws + o_kptvT);
  short*          Z      = (short*)(ws + o_Z);

  hipMemsetAsync(ws + o_xd, 0, 405504, stream);   // xd + ksum + Dv

  cvt16<<<24576, 256, 0, stream>>>((const float4*)x, x16, 6291456);
  cvt16<<<288,   256, 0, stream>>>((const float4*)w, w16, 73728);
  build_wkqvT <<<6912, 256, 0, stream>>>(kqv_w1, kqv_w2, WkqvT, WkqvN);
  build_wprojT<<<2304, 256, 0, stream>>>(proj_w1, proj_w2, (unsigned short*)WprojT);
  build_bkw   <<<3,    256, 0, stream>>>(kqv_b, w16, bkw);

  // Gw: Wkw[part][m][d] = sum_j w16[m][j] * WkqvN[d][part*768+j]  [384x768x768]x2
  mgemm<f16,128,128,8,1><<<dim3(6,3,2), 256, 0, stream>>>(
      w16, 768, 0L, WkqvN, 1536, 768L, 768, Wkw, 768, 294912L,
      nullptr, nullptr, 0L, nullptr, nullptr);

  // G1: [32768 x 2304 x 768] f16 — xd norms + V^T only (no KQ store)
  mgemm<f16,128,128,0,1><<<dim3(18,256,1), 256, 0, stream>>>(
      x16, 768, 0L, WkqvT, 768, 0L, 768, nullptr, 0, 0L, VT, kqv_b, 0L, xd, nullptr);

  // G2k: [32768 x 384 x 768] x16 @ Wkw -> kpT (+ ksum fusion)
  mgemm<f16,128,128,1,1><<<dim3(3,256,1), 256, 0, stream>>>(
      x16, 768, 0L, Wkw, 768, 0L, 768, kpT, 32768, 0L, nullptr, xd, 0L, ksum, bkw);

  // G2q: [32768 x 384 x 768] x16 @ Wqw -> qp (+ D fusion; reads ksum)
  mgemm<f16,128,128,2,1><<<dim3(3,256,1), 256, 0, stream>>>(
      x16, 768, 0L, Wkw + 294912, 768, 0L, 768, qp, 384, 0L, Dv,
      xd + NTOK, 0L, ksum, bkw + 384);

  // G3: kptv32[b*4+s][n][m] partial = V^T[b] @ kpT[b]^T over K-chunk s (split-K=4)
  mgemm<short,128,128,3,4><<<dim3(3,6,32), 256, 0, stream>>>(
      VT, 32768, 4096L, kpT, 32768, 4096L, 1024, kptv32, 384, 294912L,
      nullptr, nullptr, 0L, nullptr, nullptr);

  // reduce + transpose: kptvT[b][m][n] bf16
  reduce_kptv_t<<<dim3(12,6,8), 256, 0, stream>>>(kptv32, kptvT);

  // Gz: Z[b][j][m] = sum_n WprojT[j][n] * kptvT[b][m][n]   [768 x 384 x 768] x8
  mgemm<short,128,128,6,1><<<dim3(3,6,8), 256, 0, stream>>>(
      WprojT, 768, 0L, (short*)kptvT, 768, 294912L, 768, Z, 384, 294912L,
      nullptr, nullptr, 0L, nullptr, nullptr);

  // G45: out[t][j] = (qp[t] . Z[b][j]) / (D[t]+eps) + bias[j]   [4096 x 768 x 384] x8
  mgemm<short,128,128,7,1><<<dim3(6,32,8), 256, 0, stream>>>(
      qp, 384, 1572864L, Z, 384, 294912L, 384, d_out, 768, 3145728L,
      nullptr, Dv, 4096L, (float*)proj_b, nullptr);
}